// Round 3
// baseline (354.231 us; speedup 1.0000x reference)
//
#include <hip/hip_runtime.h>
#include <hip/hip_bf16.h>
#include <stdint.h>
#include <stddef.h>

#define B_  8192
#define T_  658
#define I_  7
#define TP  672     // T padded to multiple of 32 (GEMM1 K, A0 row stride)
#define D1_ 1024
#define D2_ 512
#define D3_ 128
#define NP4 768     // T padded to multiple of 128 (GEMM4 N)

// fused scan geometry
#define NB2 32      // batch rows per scan block
#define CT  32      // timesteps per chunk
#define NCH 21      // TP / CT
#define SCANBLKS 256            // B_ / NB2

#define CVBLKS 5376             // (D1_*TP + D2_*D1_ + D3_*D2_ + NP4*D3_)/256

typedef __bf16 bf16x8 __attribute__((ext_vector_type(8)));
typedef float  floatx4 __attribute__((ext_vector_type(4)));

__device__ __forceinline__ void gload_lds16(const void* g, void* l) {
    __builtin_amdgcn_global_load_lds(
        (const __attribute__((address_space(1))) void*)g,
        (__attribute__((address_space(3))) void*)l, 16, 0, 0);
}

__device__ __forceinline__ unsigned int pack_bf16x2(float a, float b) {
    unsigned int ua = __float_as_uint(a);
    unsigned int ub = __float_as_uint(b);
    ua += 0x7fffu + ((ua >> 16) & 1u);   // RNE to bf16 (finite inputs, |v|<=1)
    ub += 0x7fffu + ((ub >> 16) & 1u);
    return (ua >> 16) | (ub & 0xffff0000u);
}

// ------- Kernel 1 (fused): producer/consumer scan + weight conversion -------
// blocks [0, SCANBLKS): own 32 batch rows. Waves 1..3 stream x and compute the
//   I=7 projection into a double-buffered LDS [t][b] tile (BW-bound, ~2800
//   cy/chunk); wave 0 lanes 0-31 run the tanh recurrence one chunk behind
//   (latency-bound, ~900 cy/chunk) -> chain hides under the x stream.
// blocks [SCANBLKS, SCANBLKS+CVBLKS): fp32->bf16 conversion of w1..w4.
// Recurrence in r-form: r = 1/(exp2(arg)+1), h = 1-2r;
//   arg = fmaf(-2*whh*C2L, r_prev, fmaf(xv+bh, C2L, whh*C2L)) -> 4-op chain.
__global__ __launch_bounds__(256) void scan_conv_kernel(
    const float* __restrict__ x, const float* __restrict__ h0,
    const float* __restrict__ Wih, const float* __restrict__ Whh,
    const float* __restrict__ bih, const float* __restrict__ bhh,
    __bf16* __restrict__ A0, float* __restrict__ hlast,
    const float* __restrict__ w1, const float* __restrict__ w2,
    const float* __restrict__ w3, const float* __restrict__ w4,
    __bf16* __restrict__ w1b, __bf16* __restrict__ w2b,
    __bf16* __restrict__ w3b, __bf16* __restrict__ w4b) {
    if (blockIdx.x >= SCANBLKS) {
        int i = (blockIdx.x - SCANBLKS) * 256 + threadIdx.x;
        if (i < D1_ * TP) {
            int r = i / TP, c = i - r * TP;
            w1b[i] = (__bf16)(c < T_ ? w1[r * T_ + c] : 0.0f);
            return;
        }
        i -= D1_ * TP;
        if (i < D2_ * D1_) { w2b[i] = (__bf16)w2[i]; return; }
        i -= D2_ * D1_;
        if (i < D3_ * D2_) { w3b[i] = (__bf16)w3[i]; return; }
        i -= D3_ * D2_;
        {   // NP4*D3 elements
            int r = i / D3_, c = i - r * D3_;
            w4b[i] = (__bf16)(r < T_ ? w4[r * D3_ + c] : 0.0f);
        }
        return;
    }

    __shared__ float        lds_x[2][CT][NB2 + 1];   // 8448 B, [buf][t][b]
    __shared__ unsigned int lds_o[2][NB2 * 17];       // 4352 B, packed results

    const int tid = threadIdx.x;
    const int b0 = blockIdx.x * NB2;

    const float whh = Whh[0], bh = bhh[0], bi = bih[0];
    float wih[I_];
#pragma unroll
    for (int j = 0; j < I_; ++j) wih[j] = Wih[j];

    const float C2L = 2.8853900817779268f;           // 2*log2(e)
    const float whhc = whh * C2L;
    const float m2w = -2.0f * whhc;

    float h = 0.0f, r = 0.0f;
    if (tid < NB2) {
        h = h0[b0 + tid];
        r = (1.0f - h) * 0.5f;                       // r-form of the state
    }
    unsigned int res[CT / 2];

    for (int it = 0; it < NCH + 2; ++it) {
        // ---- producers: waves 1..3 fill chunk `it` into lds_x[it&1] ----
        if (it < NCH && tid >= 64) {
            const int ptid = tid - 64;               // [0,192)
            const int t0 = it * CT;
#pragma unroll
            for (int j = 0; j < 6; ++j) {
                const int cell = ptid + j * 192;     // [0, 1024)
                if (cell < NB2 * CT) {
                    const int bl = cell >> 5, tt = cell & 31;
                    const int t = t0 + tt;
                    float s = 0.0f;
                    if (t < T_) {
                        const float* xp = x + ((size_t)(b0 + bl) * T_ + t) * I_;
                        s = bi;
#pragma unroll
                        for (int i = 0; i < I_; ++i) s = fmaf(xp[i], wih[i], s);
                    }
                    lds_x[it & 1][tt][bl] = s;
                }
            }
        }
        // ---- chain: wave 0 lanes 0-31 process chunk it-1 ----
        if (tid < NB2 && it >= 1 && it <= NCH) {
            const int ck = it - 1;
            const float* lx = &lds_x[ck & 1][0][tid];
            if (ck < NCH - 1) {
#pragma unroll
                for (int k = 0; k < CT; k += 2) {
                    float xv0 = lx[k * (NB2 + 1)];
                    float xv1 = lx[(k + 1) * (NB2 + 1)];
                    float c0 = fmaf(xv0 + bh, C2L, whhc);    // off-chain
                    float c1 = fmaf(xv1 + bh, C2L, whhc);    // off-chain
                    r = __builtin_amdgcn_rcpf(__builtin_amdgcn_exp2f(fmaf(m2w, r, c0)) + 1.0f);
                    float h0v = fmaf(-2.0f, r, 1.0f);        // off-chain
                    r = __builtin_amdgcn_rcpf(__builtin_amdgcn_exp2f(fmaf(m2w, r, c1)) + 1.0f);
                    h = fmaf(-2.0f, r, 1.0f);                // off-chain
                    res[k >> 1] = pack_bf16x2(h0v, h);
                }
            } else {
                const int nval = T_ - ck * CT;   // 18 on the last chunk
#pragma unroll
                for (int k = 0; k < CT; k += 2) {
                    float r0 = 0.0f, r1 = 0.0f;
                    if (k < nval) {
                        float xv0 = lx[k * (NB2 + 1)];
                        r = __builtin_amdgcn_rcpf(
                            __builtin_amdgcn_exp2f(fmaf(m2w, r, fmaf(xv0 + bh, C2L, whhc))) + 1.0f);
                        h = fmaf(-2.0f, r, 1.0f);
                        r0 = h;
                    }
                    if (k + 1 < nval) {
                        float xv1 = lx[(k + 1) * (NB2 + 1)];
                        r = __builtin_amdgcn_rcpf(
                            __builtin_amdgcn_exp2f(fmaf(m2w, r, fmaf(xv1 + bh, C2L, whhc))) + 1.0f);
                        h = fmaf(-2.0f, r, 1.0f);
                        r1 = h;
                    }
                    res[k >> 1] = pack_bf16x2(r0, r1);
                }
            }
#pragma unroll
            for (int j = 0; j < 16; ++j) lds_o[ck & 1][tid * 17 + j] = res[j];
        }
        // ---- store: chunk it-2 (written to lds_o[(it-2)&1] last iter) ----
        if (it >= 2 && tid < 128) {
            const int ck = it - 2;
            const int bl = tid >> 2, q = tid & 3;
            uint4 v;
            v.x = lds_o[ck & 1][bl * 17 + q * 4 + 0];
            v.y = lds_o[ck & 1][bl * 17 + q * 4 + 1];
            v.z = lds_o[ck & 1][bl * 17 + q * 4 + 2];
            v.w = lds_o[ck & 1][bl * 17 + q * 4 + 3];
            *(uint4*)(A0 + (size_t)(b0 + bl) * TP + ck * CT + q * 8) = v;
        }
        __syncthreads();
    }
    if (tid < NB2) hlast[b0 + tid] = h;
}

// ---------------- Kernel 2: bf16 MFMA GEMM, C = relu(A @ W^T + bias) ---------
// BM x BN tile, BK=32, 256 threads = 4 waves in 2x2; wave tile (BM/2)x(BN/2).
// XCD-aware block decode: each XCD gets a contiguous m-range so its A panel
// is L2-resident. Requires gridDim.x % 8 == 0 for bijectivity (all satisfy).
template<int BM, int BN, int MINW>
__global__ __launch_bounds__(256, MINW) void gemm_bt(
    const __bf16* __restrict__ A, const __bf16* __restrict__ W,
    const float* __restrict__ bias, __bf16* __restrict__ outb,
    float* __restrict__ outf, int K, int Npad, int Nreal, int relu) {
    constexpr int MI = BM / 32;   // m fragments per wave
    constexpr int NJ = BN / 32;   // n fragments per wave
    constexpr int nA = BM / 64;   // 16B staging issues per thread, A tile
    constexpr int nB = BN / 64;   // 16B staging issues per thread, B tile
    __shared__ __align__(16) __bf16 As[BM * 32];
    __shared__ __align__(16) __bf16 Bs[BN * 32];

    const int tid = threadIdx.x;
    int mb, nb;
    {
        const int nbx = gridDim.x;
        const int bid = blockIdx.y * nbx + blockIdx.x;
        if ((nbx & 7) == 0) {
            const int mpx = nbx >> 3;          // m-blocks per XCD
            const int xcd = bid & 7, j = bid >> 3;
            mb = xcd * mpx + (j % mpx);
            nb = j / mpx;
        } else {
            mb = blockIdx.x; nb = blockIdx.y;
        }
    }
    const int m0 = mb * BM, n0 = nb * BN;
    const int lane = tid & 63, wave = tid >> 6;
    const int wm = (wave & 1) * (BM / 2), wn = (wave >> 1) * (BN / 2);
    const int quad = lane >> 4, l16 = lane & 15;

    const int eoff = tid * 8;
    const int rowS = eoff >> 5;            // 0..63
    const int colS = eoff & 31;
    const __bf16* gaa[nA];
    const __bf16* gbb[nB];
    __bf16* laa[nA];
    __bf16* lbb[nB];
#pragma unroll
    for (int c = 0; c < nA; ++c) {
        gaa[c] = A + (size_t)(m0 + rowS + c * 64) * K + colS;
        laa[c] = As + c * 2048 + (tid & 192) * 8;   // wave-uniform base
    }
#pragma unroll
    for (int c = 0; c < nB; ++c) {
        gbb[c] = W + (size_t)(n0 + rowS + c * 64) * K + colS;
        lbb[c] = Bs + c * 2048 + (tid & 192) * 8;
    }

    floatx4 acc[MI][NJ] = {};

    for (int k0 = 0; k0 < K; k0 += 32) {
#pragma unroll
        for (int c = 0; c < nA; ++c) gload_lds16(gaa[c] + k0, laa[c]);
#pragma unroll
        for (int c = 0; c < nB; ++c) gload_lds16(gbb[c] + k0, lbb[c]);
        __syncthreads();

        bf16x8 af[MI], bg[NJ];
#pragma unroll
        for (int i = 0; i < MI; ++i)
            af[i] = *(const bf16x8*)(As + (wm + i * 16 + l16) * 32 + quad * 8);
#pragma unroll
        for (int j = 0; j < NJ; ++j)
            bg[j] = *(const bf16x8*)(Bs + (wn + j * 16 + l16) * 32 + quad * 8);
#pragma unroll
        for (int i = 0; i < MI; ++i)
#pragma unroll
            for (int j = 0; j < NJ; ++j)
                acc[i][j] = __builtin_amdgcn_mfma_f32_16x16x32_bf16(af[i], bg[j], acc[i][j], 0, 0, 0);
        __syncthreads();
    }

    // Epilogue. C/D layout: col = lane&15, row = quad*4 + r (m89-verified)
#pragma unroll
    for (int j = 0; j < NJ; ++j) {
        const int n = n0 + wn + j * 16 + l16;
        const float bv = (n < Nreal) ? bias[n] : 0.0f;
#pragma unroll
        for (int i = 0; i < MI; ++i) {
#pragma unroll
            for (int r = 0; r < 4; ++r) {
                const int m = m0 + wm + i * 16 + quad * 4 + r;
                float v = acc[i][j][r] + bv;
                if (relu) v = fmaxf(v, 0.0f);
                if (outb) {
                    outb[(size_t)m * Npad + n] = (__bf16)v;
                } else if (n < Nreal) {
                    outf[(size_t)m * Nreal + n] = v;
                }
            }
        }
    }
}

extern "C" void kernel_launch(void* const* d_in, const int* in_sizes, int n_in,
                              void* d_out, int out_size, void* d_ws, size_t ws_size,
                              hipStream_t stream) {
    const float* x   = (const float*)d_in[0];
    const float* h0  = (const float*)d_in[1];
    const float* Wih = (const float*)d_in[2];
    const float* Whh = (const float*)d_in[3];
    const float* bih = (const float*)d_in[4];
    const float* bhh = (const float*)d_in[5];
    const float* w1  = (const float*)d_in[6];
    const float* b1  = (const float*)d_in[7];
    const float* w2  = (const float*)d_in[8];
    const float* b2  = (const float*)d_in[9];
    const float* w3  = (const float*)d_in[10];
    const float* b3  = (const float*)d_in[11];
    const float* w4  = (const float*)d_in[12];
    const float* b4  = (const float*)d_in[13];
    float* out = (float*)d_out;
    char* ws = (char*)d_ws;

    __bf16* w1b = (__bf16*)(ws + 0);          //  1,376,256
    __bf16* w2b = (__bf16*)(ws + 1376256);    //  1,048,576
    __bf16* w3b = (__bf16*)(ws + 2424832);    //    131,072
    __bf16* w4b = (__bf16*)(ws + 2555904);    //    196,608
    __bf16* A0  = (__bf16*)(ws + 2752512);    // 11,010,048  [B, TP]
    __bf16* A1  = (__bf16*)(ws + 13762560);   // 16,777,216  [B, D1]
    __bf16* A2  = (__bf16*)(ws + 30539776);   //  8,388,608  [B, D2]
    __bf16* A3  = (__bf16*)(ws + 38928384);   //  2,097,152  [B, D3]

    // Fused: scan (blocks 0..255, producer/consumer) + weight conversion
    scan_conv_kernel<<<SCANBLKS + CVBLKS, 256, 0, stream>>>(
        x, h0, Wih, Whh, bih, bhh, A0, out + (size_t)B_ * T_,
        w1, w2, w3, w4, w1b, w2b, w3b, w4b);

    // GEMM1: 128x128 tile -> 512 blocks (2/CU), the 912 TF-class structure
    gemm_bt<128,128,2><<<dim3(64, 8), 256, 0, stream>>>(A0, w1b, b1, A1, nullptr, TP,  D1_, D1_, 1);
    // GEMM2: 128x64 tile -> 512 blocks; MINW=2 (MINW=4's 128-VGPR cap risks spill)
    gemm_bt<128,64,2> <<<dim3(64, 8), 256, 0, stream>>>(A1, w2b, b2, A2, nullptr, D1_, D2_, D2_, 1);
    gemm_bt<64,64,4>  <<<dim3(128, 2), 256, 0, stream>>>(A2, w3b, b3, A3, nullptr, D2_, D3_, D3_, 1);
    gemm_bt<64,128,4> <<<dim3(128, 6), 256, 0, stream>>>(A3, w4b, b4, nullptr, out, D3_, NP4, T_, 0);
}

// Round 4
// 319.843 us; speedup vs baseline: 1.1075x; 1.1075x over previous
//
#include <hip/hip_runtime.h>
#include <hip/hip_bf16.h>
#include <stdint.h>
#include <stddef.h>

#define B_  8192
#define T_  658
#define I_  7
#define TP  672     // T padded to multiple of 32 (GEMM1 K, A0 row stride)
#define D1_ 1024
#define D2_ 512
#define D3_ 128
#define NP4 768     // T padded to multiple of 128 (GEMM4 N)

// fused scan geometry
#define NB2 32      // batch rows per scan block
#define CT  32      // timesteps per chunk
#define NCH 21      // TP / CT
#define SCANBLKS 256            // B_ / NB2

#define CVBLKS 5376             // (D1_*TP + D2_*D1_ + D3_*D2_ + NP4*D3_)/256

typedef __bf16 bf16x8 __attribute__((ext_vector_type(8)));
typedef float  floatx4 __attribute__((ext_vector_type(4)));

__device__ __forceinline__ void gload_lds16(const void* g, void* l) {
    __builtin_amdgcn_global_load_lds(
        (const __attribute__((address_space(1))) void*)g,
        (__attribute__((address_space(3))) void*)l, 16, 0, 0);
}

__device__ __forceinline__ unsigned int pack_bf16x2(float a, float b) {
    unsigned int ua = __float_as_uint(a);
    unsigned int ub = __float_as_uint(b);
    ua += 0x7fffu + ((ua >> 16) & 1u);   // RNE to bf16 (finite inputs, |v|<=1)
    ub += 0x7fffu + ((ub >> 16) & 1u);
    return (ua >> 16) | (ub & 0xffff0000u);
}

// ------- Kernel 1 (fused): producer/consumer scan + weight conversion -------
// blocks [0, SCANBLKS): own 32 batch rows. Waves 1..3 produce the I=7
//   projection into a double-buffered LDS [t][b] tile; wave 0 lanes 0-31 run
//   the tanh recurrence one chunk behind.
// Producer (R4 fix): unit = 4 timesteps = 28 contiguous floats of one x row,
//   loaded as 14 independent float2 (8B-aligned: row stride 18424 B = 8 mod 16,
//   unit offset 112*(8c+u) B = 0 mod 16). 256 units/chunk over 192 threads.
//   Raises per-thread MLP ~2 -> 14-28 outstanding loads (R3: VGPR=32, 851 GB/s,
//   latency-bound at 12.5k cy/chunk).
// blocks [SCANBLKS, SCANBLKS+CVBLKS): fp32->bf16 conversion of w1..w4.
// Recurrence in r-form: r = 1/(exp2(arg)+1), h = 1-2r;
//   arg = fmaf(-2*whh*C2L, r_prev, fmaf(xv+bh, C2L, whh*C2L)) -> 4-op chain.
__global__ __launch_bounds__(256) void scan_conv_kernel(
    const float* __restrict__ x, const float* __restrict__ h0,
    const float* __restrict__ Wih, const float* __restrict__ Whh,
    const float* __restrict__ bih, const float* __restrict__ bhh,
    __bf16* __restrict__ A0, float* __restrict__ hlast,
    const float* __restrict__ w1, const float* __restrict__ w2,
    const float* __restrict__ w3, const float* __restrict__ w4,
    __bf16* __restrict__ w1b, __bf16* __restrict__ w2b,
    __bf16* __restrict__ w3b, __bf16* __restrict__ w4b) {
    if (blockIdx.x >= SCANBLKS) {
        int i = (blockIdx.x - SCANBLKS) * 256 + threadIdx.x;
        if (i < D1_ * TP) {
            int r = i / TP, c = i - r * TP;
            w1b[i] = (__bf16)(c < T_ ? w1[r * T_ + c] : 0.0f);
            return;
        }
        i -= D1_ * TP;
        if (i < D2_ * D1_) { w2b[i] = (__bf16)w2[i]; return; }
        i -= D2_ * D1_;
        if (i < D3_ * D2_) { w3b[i] = (__bf16)w3[i]; return; }
        i -= D3_ * D2_;
        {   // NP4*D3 elements
            int r = i / D3_, c = i - r * D3_;
            w4b[i] = (__bf16)(r < T_ ? w4[r * D3_ + c] : 0.0f);
        }
        return;
    }

    __shared__ float        lds_x[2][CT][NB2 + 1];   // 8448 B, [buf][t][b]
    __shared__ unsigned int lds_o[2][NB2 * 17];       // 4352 B, packed results

    const int tid = threadIdx.x;
    const int b0 = blockIdx.x * NB2;

    const float whh = Whh[0], bh = bhh[0], bi = bih[0];
    float wih[I_];
#pragma unroll
    for (int j = 0; j < I_; ++j) wih[j] = Wih[j];

    const float C2L = 2.8853900817779268f;           // 2*log2(e)
    const float whhc = whh * C2L;
    const float m2w = -2.0f * whhc;

    float h = 0.0f, r = 0.0f;
    if (tid < NB2) {
        h = h0[b0 + tid];
        r = (1.0f - h) * 0.5f;                       // r-form of the state
    }
    unsigned int res[CT / 2];

    for (int it = 0; it < NCH + 2; ++it) {
        // ---- producers: waves 1..3 fill chunk `it` into lds_x[it&1] ----
        if (it < NCH && tid >= 64) {
            const int t0 = it * CT;
#pragma unroll
            for (int j = 0; j < 2; ++j) {
                const int unit = (tid - 64) + j * 192;   // [0, 256)
                if (unit < NB2 * 8) {
                    const int row = unit >> 3, u = unit & 7;
                    const int tb = t0 + u * 4;           // first timestep of unit
                    const float* gp = x + (size_t)(b0 + row) * (T_ * I_)
                                        + (size_t)tb * I_;
                    float xr[28];
                    if (tb <= T_ - 4) {
                        // 14 independent 8B loads, all issued before any use
#pragma unroll
                        for (int k = 0; k < 14; ++k) {
                            const float2 f = *(const float2*)(gp + 2 * k);
                            xr[2 * k]     = f.x;
                            xr[2 * k + 1] = f.y;
                        }
                    } else {
                        // last-chunk tail units: per-element guard vs end of row
                        const int nfl = (T_ - tb) * I_;  // may be <= 0
#pragma unroll
                        for (int k = 0; k < 28; ++k)
                            xr[k] = (k < nfl) ? gp[k] : 0.0f;
                    }
#pragma unroll
                    for (int n = 0; n < 4; ++n) {
                        float s = bi;
#pragma unroll
                        for (int i = 0; i < I_; ++i)
                            s = fmaf(xr[n * 7 + i], wih[i], s);
                        lds_x[it & 1][u * 4 + n][row] = s;
                    }
                }
            }
        }
        // ---- chain: wave 0 lanes 0-31 process chunk it-1 ----
        if (tid < NB2 && it >= 1 && it <= NCH) {
            const int ck = it - 1;
            const float* lx = &lds_x[ck & 1][0][tid];
            if (ck < NCH - 1) {
#pragma unroll
                for (int k = 0; k < CT; k += 2) {
                    float xv0 = lx[k * (NB2 + 1)];
                    float xv1 = lx[(k + 1) * (NB2 + 1)];
                    float c0 = fmaf(xv0 + bh, C2L, whhc);    // off-chain
                    float c1 = fmaf(xv1 + bh, C2L, whhc);    // off-chain
                    r = __builtin_amdgcn_rcpf(__builtin_amdgcn_exp2f(fmaf(m2w, r, c0)) + 1.0f);
                    float h0v = fmaf(-2.0f, r, 1.0f);        // off-chain
                    r = __builtin_amdgcn_rcpf(__builtin_amdgcn_exp2f(fmaf(m2w, r, c1)) + 1.0f);
                    h = fmaf(-2.0f, r, 1.0f);                // off-chain
                    res[k >> 1] = pack_bf16x2(h0v, h);
                }
            } else {
                const int nval = T_ - ck * CT;   // 18 on the last chunk
#pragma unroll
                for (int k = 0; k < CT; k += 2) {
                    float r0 = 0.0f, r1 = 0.0f;
                    if (k < nval) {
                        float xv0 = lx[k * (NB2 + 1)];
                        r = __builtin_amdgcn_rcpf(
                            __builtin_amdgcn_exp2f(fmaf(m2w, r, fmaf(xv0 + bh, C2L, whhc))) + 1.0f);
                        h = fmaf(-2.0f, r, 1.0f);
                        r0 = h;
                    }
                    if (k + 1 < nval) {
                        float xv1 = lx[(k + 1) * (NB2 + 1)];
                        r = __builtin_amdgcn_rcpf(
                            __builtin_amdgcn_exp2f(fmaf(m2w, r, fmaf(xv1 + bh, C2L, whhc))) + 1.0f);
                        h = fmaf(-2.0f, r, 1.0f);
                        r1 = h;
                    }
                    res[k >> 1] = pack_bf16x2(r0, r1);
                }
            }
#pragma unroll
            for (int j = 0; j < 16; ++j) lds_o[ck & 1][tid * 17 + j] = res[j];
        }
        // ---- store: chunk it-2 (written to lds_o[(it-2)&1] last iter) ----
        if (it >= 2 && tid < 128) {
            const int ck = it - 2;
            const int bl = tid >> 2, q = tid & 3;
            uint4 v;
            v.x = lds_o[ck & 1][bl * 17 + q * 4 + 0];
            v.y = lds_o[ck & 1][bl * 17 + q * 4 + 1];
            v.z = lds_o[ck & 1][bl * 17 + q * 4 + 2];
            v.w = lds_o[ck & 1][bl * 17 + q * 4 + 3];
            *(uint4*)(A0 + (size_t)(b0 + bl) * TP + ck * CT + q * 8) = v;
        }
        __syncthreads();
    }
    if (tid < NB2) hlast[b0 + tid] = h;
}

// ---------------- Kernel 2: bf16 MFMA GEMM, C = relu(A @ W^T + bias) ---------
// BM x BN tile, BK=32, 256 threads = 4 waves in 2x2; wave tile (BM/2)x(BN/2).
// XCD-aware block decode: each XCD gets a contiguous m-range so its A panel
// is L2-resident. Requires gridDim.x % 8 == 0 for bijectivity (all satisfy).
template<int BM, int BN, int MINW>
__global__ __launch_bounds__(256, MINW) void gemm_bt(
    const __bf16* __restrict__ A, const __bf16* __restrict__ W,
    const float* __restrict__ bias, __bf16* __restrict__ outb,
    float* __restrict__ outf, int K, int Npad, int Nreal, int relu) {
    constexpr int MI = BM / 32;   // m fragments per wave
    constexpr int NJ = BN / 32;   // n fragments per wave
    constexpr int nA = BM / 64;   // 16B staging issues per thread, A tile
    constexpr int nB = BN / 64;   // 16B staging issues per thread, B tile
    __shared__ __align__(16) __bf16 As[BM * 32];
    __shared__ __align__(16) __bf16 Bs[BN * 32];

    const int tid = threadIdx.x;
    int mb, nb;
    {
        const int nbx = gridDim.x;
        const int bid = blockIdx.y * nbx + blockIdx.x;
        if ((nbx & 7) == 0) {
            const int mpx = nbx >> 3;          // m-blocks per XCD
            const int xcd = bid & 7, j = bid >> 3;
            mb = xcd * mpx + (j % mpx);
            nb = j / mpx;
        } else {
            mb = blockIdx.x; nb = blockIdx.y;
        }
    }
    const int m0 = mb * BM, n0 = nb * BN;
    const int lane = tid & 63, wave = tid >> 6;
    const int wm = (wave & 1) * (BM / 2), wn = (wave >> 1) * (BN / 2);
    const int quad = lane >> 4, l16 = lane & 15;

    const int eoff = tid * 8;
    const int rowS = eoff >> 5;            // 0..63
    const int colS = eoff & 31;
    const __bf16* gaa[nA];
    const __bf16* gbb[nB];
    __bf16* laa[nA];
    __bf16* lbb[nB];
#pragma unroll
    for (int c = 0; c < nA; ++c) {
        gaa[c] = A + (size_t)(m0 + rowS + c * 64) * K + colS;
        laa[c] = As + c * 2048 + (tid & 192) * 8;   // wave-uniform base
    }
#pragma unroll
    for (int c = 0; c < nB; ++c) {
        gbb[c] = W + (size_t)(n0 + rowS + c * 64) * K + colS;
        lbb[c] = Bs + c * 2048 + (tid & 192) * 8;
    }

    floatx4 acc[MI][NJ] = {};

    for (int k0 = 0; k0 < K; k0 += 32) {
#pragma unroll
        for (int c = 0; c < nA; ++c) gload_lds16(gaa[c] + k0, laa[c]);
#pragma unroll
        for (int c = 0; c < nB; ++c) gload_lds16(gbb[c] + k0, lbb[c]);
        __syncthreads();

        bf16x8 af[MI], bg[NJ];
#pragma unroll
        for (int i = 0; i < MI; ++i)
            af[i] = *(const bf16x8*)(As + (wm + i * 16 + l16) * 32 + quad * 8);
#pragma unroll
        for (int j = 0; j < NJ; ++j)
            bg[j] = *(const bf16x8*)(Bs + (wn + j * 16 + l16) * 32 + quad * 8);
#pragma unroll
        for (int i = 0; i < MI; ++i)
#pragma unroll
            for (int j = 0; j < NJ; ++j)
                acc[i][j] = __builtin_amdgcn_mfma_f32_16x16x32_bf16(af[i], bg[j], acc[i][j], 0, 0, 0);
        __syncthreads();
    }

    // Epilogue. C/D layout: col = lane&15, row = quad*4 + r (m89-verified)
#pragma unroll
    for (int j = 0; j < NJ; ++j) {
        const int n = n0 + wn + j * 16 + l16;
        const float bv = (n < Nreal) ? bias[n] : 0.0f;
#pragma unroll
        for (int i = 0; i < MI; ++i) {
#pragma unroll
            for (int r = 0; r < 4; ++r) {
                const int m = m0 + wm + i * 16 + quad * 4 + r;
                float v = acc[i][j][r] + bv;
                if (relu) v = fmaxf(v, 0.0f);
                if (outb) {
                    outb[(size_t)m * Npad + n] = (__bf16)v;
                } else if (n < Nreal) {
                    outf[(size_t)m * Nreal + n] = v;
                }
            }
        }
    }
}

extern "C" void kernel_launch(void* const* d_in, const int* in_sizes, int n_in,
                              void* d_out, int out_size, void* d_ws, size_t ws_size,
                              hipStream_t stream) {
    const float* x   = (const float*)d_in[0];
    const float* h0  = (const float*)d_in[1];
    const float* Wih = (const float*)d_in[2];
    const float* Whh = (const float*)d_in[3];
    const float* bih = (const float*)d_in[4];
    const float* bhh = (const float*)d_in[5];
    const float* w1  = (const float*)d_in[6];
    const float* b1  = (const float*)d_in[7];
    const float* w2  = (const float*)d_in[8];
    const float* b2  = (const float*)d_in[9];
    const float* w3  = (const float*)d_in[10];
    const float* b3  = (const float*)d_in[11];
    const float* w4  = (const float*)d_in[12];
    const float* b4  = (const float*)d_in[13];
    float* out = (float*)d_out;
    char* ws = (char*)d_ws;

    __bf16* w1b = (__bf16*)(ws + 0);          //  1,376,256
    __bf16* w2b = (__bf16*)(ws + 1376256);    //  1,048,576
    __bf16* w3b = (__bf16*)(ws + 2424832);    //    131,072
    __bf16* w4b = (__bf16*)(ws + 2555904);    //    196,608
    __bf16* A0  = (__bf16*)(ws + 2752512);    // 11,010,048  [B, TP]
    __bf16* A1  = (__bf16*)(ws + 13762560);   // 16,777,216  [B, D1]
    __bf16* A2  = (__bf16*)(ws + 30539776);   //  8,388,608  [B, D2]
    __bf16* A3  = (__bf16*)(ws + 38928384);   //  2,097,152  [B, D3]

    // Fused: scan (blocks 0..255, producer/consumer) + weight conversion
    scan_conv_kernel<<<SCANBLKS + CVBLKS, 256, 0, stream>>>(
        x, h0, Wih, Whh, bih, bhh, A0, out + (size_t)B_ * T_,
        w1, w2, w3, w4, w1b, w2b, w3b, w4b);

    // GEMM1: 128x128 tile -> 512 blocks (2/CU), the 912 TF-class structure
    gemm_bt<128,128,2><<<dim3(64, 8), 256, 0, stream>>>(A0, w1b, b1, A1, nullptr, TP,  D1_, D1_, 1);
    // GEMM2: 128x64 tile -> 512 blocks; MINW=2 (MINW=4's 128-VGPR cap risks spill)
    gemm_bt<128,64,2> <<<dim3(64, 8), 256, 0, stream>>>(A1, w2b, b2, A2, nullptr, D1_, D2_, D2_, 1);
    gemm_bt<64,64,4>  <<<dim3(128, 2), 256, 0, stream>>>(A2, w3b, b3, A3, nullptr, D2_, D3_, D3_, 1);
    gemm_bt<64,128,4> <<<dim3(128, 6), 256, 0, stream>>>(A3, w4b, b4, nullptr, out, D3_, NP4, T_, 0);
}

// Round 5
// 315.412 us; speedup vs baseline: 1.1231x; 1.0140x over previous
//
#include <hip/hip_runtime.h>
#include <hip/hip_bf16.h>
#include <stdint.h>
#include <stddef.h>

#define B_  8192
#define T_  658
#define I_  7
#define TP  672     // T padded to multiple of 32 (GEMM1 K, A0 row stride)
#define D1_ 1024
#define D2_ 512
#define D3_ 128
#define NP4 768     // T padded to multiple of 128 (GEMM4 N)

// fused scan geometry
#define NB2 32      // batch rows per scan block
#define CT  32      // timesteps per chunk
#define NCH 21      // TP / CT
#define SCANBLKS 256            // B_ / NB2
#define SCTHR 320               // scan block threads: 1 consumer + 4 producer waves

#define CVTOT (D1_*TP + D2_*D1_ + D3_*D2_ + NP4*D3_)   // 1,376,256
#define CVBLKS ((CVTOT + SCTHR - 1) / SCTHR)            // 4301

typedef __bf16 bf16x8 __attribute__((ext_vector_type(8)));
typedef float  floatx4 __attribute__((ext_vector_type(4)));

__device__ __forceinline__ void gload_lds16(const void* g, void* l) {
    __builtin_amdgcn_global_load_lds(
        (const __attribute__((address_space(1))) void*)g,
        (__attribute__((address_space(3))) void*)l, 16, 0, 0);
}

__device__ __forceinline__ unsigned int pack_bf16x2(float a, float b) {
    unsigned int ua = __float_as_uint(a);
    unsigned int ub = __float_as_uint(b);
    ua += 0x7fffu + ((ua >> 16) & 1u);   // RNE to bf16 (finite inputs, |v|<=1)
    ub += 0x7fffu + ((ub >> 16) & 1u);
    return (ua >> 16) | (ub & 0xffff0000u);
}

// Load one unit (4 timesteps = 28 contiguous floats, 8B-aligned) of row data.
// tb = first timestep of the unit; guarded path only on the last chunk.
__device__ __forceinline__ void load_unit(const float* __restrict__ gp, int tb,
                                          float* __restrict__ xr) {
    if (tb <= T_ - 4) {
#pragma unroll
        for (int k = 0; k < 14; ++k) {       // 14 independent 8B loads
            const float2 f = *(const float2*)(gp + 2 * k);
            xr[2 * k]     = f.x;
            xr[2 * k + 1] = f.y;
        }
    } else {
        const int nfl = (T_ - tb) * I_;      // may be <= 0
#pragma unroll
        for (int k = 0; k < 28; ++k)
            xr[k] = (k < nfl) ? gp[k] : 0.0f;
    }
}

// ------- Kernel 1 (fused): producer/consumer scan + weight conversion -------
// blocks [0, SCANBLKS): own 32 batch rows, 320 threads.
//   Waves 1..4 = 256 producer threads, EXACTLY 1 unit (4 timesteps x 1 row)
//   each per chunk: no divergence, no double duty (R4 defect 1). Register
//   prefetch one chunk ahead: iteration it writes chunk it from regs to LDS,
//   then issues chunk it+1's loads; the ~900cy latency hides across the
//   barrier (loads target VGPRs -> no forced vmcnt drain at __syncthreads).
//   Wave 0 lanes 0-31 run the tanh recurrence one chunk behind.
// blocks [SCANBLKS, ...): fp32->bf16 conversion of w1..w4 (320-thread map).
// Recurrence in r-form: r = 1/(exp2(arg)+1), h = 1-2r;
//   arg = fmaf(-2*whh*C2L, r_prev, fmaf(xv+bh, C2L, whh*C2L)) -> 4-op chain.
__global__ __launch_bounds__(SCTHR) void scan_conv_kernel(
    const float* __restrict__ x, const float* __restrict__ h0,
    const float* __restrict__ Wih, const float* __restrict__ Whh,
    const float* __restrict__ bih, const float* __restrict__ bhh,
    __bf16* __restrict__ A0, float* __restrict__ hlast,
    const float* __restrict__ w1, const float* __restrict__ w2,
    const float* __restrict__ w3, const float* __restrict__ w4,
    __bf16* __restrict__ w1b, __bf16* __restrict__ w2b,
    __bf16* __restrict__ w3b, __bf16* __restrict__ w4b) {
    if (blockIdx.x >= SCANBLKS) {
        int i = (blockIdx.x - SCANBLKS) * SCTHR + threadIdx.x;
        if (i < D1_ * TP) {
            int r = i / TP, c = i - r * TP;
            w1b[i] = (__bf16)(c < T_ ? w1[r * T_ + c] : 0.0f);
            return;
        }
        i -= D1_ * TP;
        if (i < D2_ * D1_) { w2b[i] = (__bf16)w2[i]; return; }
        i -= D2_ * D1_;
        if (i < D3_ * D2_) { w3b[i] = (__bf16)w3[i]; return; }
        i -= D3_ * D2_;
        if (i < NP4 * D3_) {
            int r = i / D3_, c = i - r * D3_;
            w4b[i] = (__bf16)(r < T_ ? w4[r * D3_ + c] : 0.0f);
        }
        return;
    }

    __shared__ float        lds_x[2][CT][NB2 + 1];   // 8448 B, [buf][t][b]
    __shared__ unsigned int lds_o[2][NB2 * 17];       // 4352 B, packed results

    const int tid = threadIdx.x;
    const int b0 = blockIdx.x * NB2;

    const float whh = Whh[0], bh = bhh[0], bi = bih[0];
    float wih[I_];
#pragma unroll
    for (int j = 0; j < I_; ++j) wih[j] = Wih[j];

    const float C2L = 2.8853900817779268f;           // 2*log2(e)
    const float whhc = whh * C2L;
    const float m2w = -2.0f * whhc;

    float h = 0.0f, r = 0.0f;
    if (tid < NB2) {
        h = h0[b0 + tid];
        r = (1.0f - h) * 0.5f;                       // r-form of the state
    }
    unsigned int res[CT / 2];

    // producer geometry: unit = tid-64 in [0,256); row = unit>>3, u = unit&7
    const int unit = tid - 64;
    const int prow = unit >> 3, pu = unit & 7;
    const float* gpu = x + (size_t)(b0 + prow) * (T_ * I_) + (size_t)(pu * 4) * I_;
    float xr[28];
    if (tid >= 64) load_unit(gpu, pu * 4, xr);       // prologue: chunk 0

    for (int it = 0; it < NCH + 2; ++it) {
        // ---- producers: write chunk `it` (in regs) to lds_x[it&1], then
        //      issue chunk it+1's loads (latency spans the barrier) ----
        if (tid >= 64 && it < NCH) {
#pragma unroll
            for (int n = 0; n < 4; ++n) {
                float s = bi;
#pragma unroll
                for (int i = 0; i < I_; ++i)
                    s = fmaf(xr[n * 7 + i], wih[i], s);
                lds_x[it & 1][pu * 4 + n][prow] = s;
            }
            if (it + 1 < NCH)
                load_unit(gpu + (size_t)(it + 1) * (CT * I_),
                          (it + 1) * CT + pu * 4, xr);
        }
        // ---- chain: wave 0 lanes 0-31 process chunk it-1 ----
        if (tid < NB2 && it >= 1 && it <= NCH) {
            const int ck = it - 1;
            const float* lx = &lds_x[ck & 1][0][tid];
            if (ck < NCH - 1) {
#pragma unroll
                for (int k = 0; k < CT; k += 2) {
                    float xv0 = lx[k * (NB2 + 1)];
                    float xv1 = lx[(k + 1) * (NB2 + 1)];
                    float c0 = fmaf(xv0 + bh, C2L, whhc);    // off-chain
                    float c1 = fmaf(xv1 + bh, C2L, whhc);    // off-chain
                    r = __builtin_amdgcn_rcpf(__builtin_amdgcn_exp2f(fmaf(m2w, r, c0)) + 1.0f);
                    float h0v = fmaf(-2.0f, r, 1.0f);        // off-chain
                    r = __builtin_amdgcn_rcpf(__builtin_amdgcn_exp2f(fmaf(m2w, r, c1)) + 1.0f);
                    h = fmaf(-2.0f, r, 1.0f);                // off-chain
                    res[k >> 1] = pack_bf16x2(h0v, h);
                }
            } else {
                const int nval = T_ - ck * CT;   // 18 on the last chunk
#pragma unroll
                for (int k = 0; k < CT; k += 2) {
                    float r0 = 0.0f, r1 = 0.0f;
                    if (k < nval) {
                        float xv0 = lx[k * (NB2 + 1)];
                        r = __builtin_amdgcn_rcpf(
                            __builtin_amdgcn_exp2f(fmaf(m2w, r, fmaf(xv0 + bh, C2L, whhc))) + 1.0f);
                        h = fmaf(-2.0f, r, 1.0f);
                        r0 = h;
                    }
                    if (k + 1 < nval) {
                        float xv1 = lx[(k + 1) * (NB2 + 1)];
                        r = __builtin_amdgcn_rcpf(
                            __builtin_amdgcn_exp2f(fmaf(m2w, r, fmaf(xv1 + bh, C2L, whhc))) + 1.0f);
                        h = fmaf(-2.0f, r, 1.0f);
                        r1 = h;
                    }
                    res[k >> 1] = pack_bf16x2(r0, r1);
                }
            }
#pragma unroll
            for (int j = 0; j < 16; ++j) lds_o[ck & 1][tid * 17 + j] = res[j];
        }
        // ---- store: chunk it-2 (written to lds_o[(it-2)&1] last iter) ----
        if (it >= 2 && tid < 128) {
            const int ck = it - 2;
            const int bl = tid >> 2, q = tid & 3;
            uint4 v;
            v.x = lds_o[ck & 1][bl * 17 + q * 4 + 0];
            v.y = lds_o[ck & 1][bl * 17 + q * 4 + 1];
            v.z = lds_o[ck & 1][bl * 17 + q * 4 + 2];
            v.w = lds_o[ck & 1][bl * 17 + q * 4 + 3];
            *(uint4*)(A0 + (size_t)(b0 + bl) * TP + ck * CT + q * 8) = v;
        }
        __syncthreads();
    }
    if (tid < NB2) hlast[b0 + tid] = h;
}

// ---------------- Kernel 2: bf16 MFMA GEMM, C = relu(A @ W^T + bias) ---------
// BM x BN tile, BK=32, 256 threads = 4 waves in 2x2; wave tile (BM/2)x(BN/2).
// XCD-aware block decode: each XCD gets a contiguous m-range so its A panel
// is L2-resident. Requires gridDim.x % 8 == 0 for bijectivity (all satisfy).
template<int BM, int BN, int MINW>
__global__ __launch_bounds__(256, MINW) void gemm_bt(
    const __bf16* __restrict__ A, const __bf16* __restrict__ W,
    const float* __restrict__ bias, __bf16* __restrict__ outb,
    float* __restrict__ outf, int K, int Npad, int Nreal, int relu) {
    constexpr int MI = BM / 32;   // m fragments per wave
    constexpr int NJ = BN / 32;   // n fragments per wave
    constexpr int nA = BM / 64;   // 16B staging issues per thread, A tile
    constexpr int nB = BN / 64;   // 16B staging issues per thread, B tile
    __shared__ __align__(16) __bf16 As[BM * 32];
    __shared__ __align__(16) __bf16 Bs[BN * 32];

    const int tid = threadIdx.x;
    int mb, nb;
    {
        const int nbx = gridDim.x;
        const int bid = blockIdx.y * nbx + blockIdx.x;
        if ((nbx & 7) == 0) {
            const int mpx = nbx >> 3;          // m-blocks per XCD
            const int xcd = bid & 7, j = bid >> 3;
            mb = xcd * mpx + (j % mpx);
            nb = j / mpx;
        } else {
            mb = blockIdx.x; nb = blockIdx.y;
        }
    }
    const int m0 = mb * BM, n0 = nb * BN;
    const int lane = tid & 63, wave = tid >> 6;
    const int wm = (wave & 1) * (BM / 2), wn = (wave >> 1) * (BN / 2);
    const int quad = lane >> 4, l16 = lane & 15;

    const int eoff = tid * 8;
    const int rowS = eoff >> 5;            // 0..63
    const int colS = eoff & 31;
    const __bf16* gaa[nA];
    const __bf16* gbb[nB];
    __bf16* laa[nA];
    __bf16* lbb[nB];
#pragma unroll
    for (int c = 0; c < nA; ++c) {
        gaa[c] = A + (size_t)(m0 + rowS + c * 64) * K + colS;
        laa[c] = As + c * 2048 + (tid & 192) * 8;   // wave-uniform base
    }
#pragma unroll
    for (int c = 0; c < nB; ++c) {
        gbb[c] = W + (size_t)(n0 + rowS + c * 64) * K + colS;
        lbb[c] = Bs + c * 2048 + (tid & 192) * 8;
    }

    floatx4 acc[MI][NJ] = {};

    for (int k0 = 0; k0 < K; k0 += 32) {
#pragma unroll
        for (int c = 0; c < nA; ++c) gload_lds16(gaa[c] + k0, laa[c]);
#pragma unroll
        for (int c = 0; c < nB; ++c) gload_lds16(gbb[c] + k0, lbb[c]);
        __syncthreads();

        bf16x8 af[MI], bg[NJ];
#pragma unroll
        for (int i = 0; i < MI; ++i)
            af[i] = *(const bf16x8*)(As + (wm + i * 16 + l16) * 32 + quad * 8);
#pragma unroll
        for (int j = 0; j < NJ; ++j)
            bg[j] = *(const bf16x8*)(Bs + (wn + j * 16 + l16) * 32 + quad * 8);
#pragma unroll
        for (int i = 0; i < MI; ++i)
#pragma unroll
            for (int j = 0; j < NJ; ++j)
                acc[i][j] = __builtin_amdgcn_mfma_f32_16x16x32_bf16(af[i], bg[j], acc[i][j], 0, 0, 0);
        __syncthreads();
    }

    // Epilogue. C/D layout: col = lane&15, row = quad*4 + r (m89-verified)
#pragma unroll
    for (int j = 0; j < NJ; ++j) {
        const int n = n0 + wn + j * 16 + l16;
        const float bv = (n < Nreal) ? bias[n] : 0.0f;
#pragma unroll
        for (int i = 0; i < MI; ++i) {
#pragma unroll
            for (int r = 0; r < 4; ++r) {
                const int m = m0 + wm + i * 16 + quad * 4 + r;
                float v = acc[i][j][r] + bv;
                if (relu) v = fmaxf(v, 0.0f);
                if (outb) {
                    outb[(size_t)m * Npad + n] = (__bf16)v;
                } else if (n < Nreal) {
                    outf[(size_t)m * Nreal + n] = v;
                }
            }
        }
    }
}

extern "C" void kernel_launch(void* const* d_in, const int* in_sizes, int n_in,
                              void* d_out, int out_size, void* d_ws, size_t ws_size,
                              hipStream_t stream) {
    const float* x   = (const float*)d_in[0];
    const float* h0  = (const float*)d_in[1];
    const float* Wih = (const float*)d_in[2];
    const float* Whh = (const float*)d_in[3];
    const float* bih = (const float*)d_in[4];
    const float* bhh = (const float*)d_in[5];
    const float* w1  = (const float*)d_in[6];
    const float* b1  = (const float*)d_in[7];
    const float* w2  = (const float*)d_in[8];
    const float* b2  = (const float*)d_in[9];
    const float* w3  = (const float*)d_in[10];
    const float* b3  = (const float*)d_in[11];
    const float* w4  = (const float*)d_in[12];
    const float* b4  = (const float*)d_in[13];
    float* out = (float*)d_out;
    char* ws = (char*)d_ws;

    __bf16* w1b = (__bf16*)(ws + 0);          //  1,376,256
    __bf16* w2b = (__bf16*)(ws + 1376256);    //  1,048,576
    __bf16* w3b = (__bf16*)(ws + 2424832);    //    131,072
    __bf16* w4b = (__bf16*)(ws + 2555904);    //    196,608
    __bf16* A0  = (__bf16*)(ws + 2752512);    // 11,010,048  [B, TP]
    __bf16* A1  = (__bf16*)(ws + 13762560);   // 16,777,216  [B, D1]
    __bf16* A2  = (__bf16*)(ws + 30539776);   //  8,388,608  [B, D2]
    __bf16* A3  = (__bf16*)(ws + 38928384);   //  2,097,152  [B, D3]

    // Fused: scan (blocks 0..255, producer/consumer) + weight conversion
    scan_conv_kernel<<<SCANBLKS + CVBLKS, SCTHR, 0, stream>>>(
        x, h0, Wih, Whh, bih, bhh, A0, out + (size_t)B_ * T_,
        w1, w2, w3, w4, w1b, w2b, w3b, w4b);

    // GEMM1: 128x128 tile -> 512 blocks (2/CU), the 912 TF-class structure
    gemm_bt<128,128,2><<<dim3(64, 8), 256, 0, stream>>>(A0, w1b, b1, A1, nullptr, TP,  D1_, D1_, 1);
    // GEMM2: 128x64 tile -> 512 blocks; MINW=2 (MINW=4's 128-VGPR cap risks spill)
    gemm_bt<128,64,2> <<<dim3(64, 8), 256, 0, stream>>>(A1, w2b, b2, A2, nullptr, D1_, D2_, D2_, 1);
    gemm_bt<64,64,4>  <<<dim3(128, 2), 256, 0, stream>>>(A2, w3b, b3, A3, nullptr, D2_, D3_, D3_, 1);
    gemm_bt<64,128,4> <<<dim3(128, 6), 256, 0, stream>>>(A3, w4b, b4, nullptr, out, D3_, NP4, T_, 0);
}